// Round 15
// baseline (333.052 us; speedup 1.0000x reference)
//
#include <hip/hip_runtime.h>
#include <hip/hip_bf16.h>

static constexpr int Bsz = 2;
static constexpr int Tn  = 2048;
static constexpr int Dn  = 2048;
static constexpr int Hn  = 16;
static constexpr int Ln  = 64;
static constexpr int Hd  = 128;
static constexpr float SL2E = 0.125f * 1.44269504088896f;  // SCALE * log2(e)

typedef short short8 __attribute__((ext_vector_type(8)));
typedef float f32x4 __attribute__((ext_vector_type(4)));
typedef unsigned short ushort8 __attribute__((ext_vector_type(8)));
typedef unsigned short ushort4v __attribute__((ext_vector_type(4)));
typedef _Float16 half8 __attribute__((ext_vector_type(8)));
typedef unsigned short u16;

__device__ inline u16 f16_rne(float f) {
  _Float16 h = (_Float16)f;  // RNE
  union { _Float16 h; u16 u; } x; x.h = h;
  return x.u;
}
__device__ inline float f16_to_f(u16 u) {
  union { u16 u; _Float16 h; } x; x.u = u;
  return (float)x.h;
}

#define GL(g, l) __builtin_amdgcn_global_load_lds(                     \
    (const __attribute__((address_space(1))) void*)(g),                \
    (__attribute__((address_space(3))) void*)(l), 16, 0, 0)

// ---------- fp32 -> fp16 with per-32 K-window permutation ------------------
__global__ void split_h(const float* __restrict__ A, u16* __restrict__ O,
                        int nblk, int Kd) {
  int b = blockIdx.x * 256 + threadIdx.x;
  if (b >= nblk) return;
  int perRow = Kd >> 3;
  int m = b / perRow, gb = b - m * perRow;
  int w = gb >> 2, g = gb & 3;
  const float* src = A + (size_t)m * Kd + (w << 5) + (g << 2);
  float4 v0 = *(const float4*)src;
  float4 v1 = *(const float4*)(src + 16);
  float e[8] = {v0.x, v0.y, v0.z, v0.w, v1.x, v1.y, v1.z, v1.w};
  ushort8 o;
#pragma unroll
  for (int j = 0; j < 8; ++j) o[j] = f16_rne(e[j]);
  *(ushort8*)(O + (size_t)b * 8) = o;
}

// ---------- transpose W[K][N] -> WT[N][K] fp16, K-permuted (paired) --------
__global__ __launch_bounds__(256) void transpose_h2(
    const float* __restrict__ W0, const float* __restrict__ W1,
    u16* __restrict__ T0, u16* __restrict__ T1, int Kd, int Nd) {
  const float* W = blockIdx.z ? W1 : W0;
  u16* Th = blockIdx.z ? T1 : T0;
  __shared__ float t[32][33];
  int k0 = blockIdx.x * 32, n0 = blockIdx.y * 32;
  int i = threadIdx.x;
  {
    int kk = i >> 3, nn = (i & 7) << 2;
    float4 v = *(const float4*)&W[(size_t)(k0 + kk) * Nd + n0 + nn];
    t[kk][nn] = v.x; t[kk][nn + 1] = v.y; t[kk][nn + 2] = v.z; t[kk][nn + 3] = v.w;
  }
  __syncthreads();
  int n = i >> 3, t2 = i & 7;
  int g = t2 >> 1, h = t2 & 1;
  int kbase = h * 16 + g * 4;
  ushort4v o;
#pragma unroll
  for (int j = 0; j < 4; ++j) o[j] = f16_rne(t[kbase + j][n]);
  *(ushort4v*)(Th + (size_t)(n0 + n) * Kd + k0 + t2 * 4) = o;
}

// ---------- generic 64x64-tile fp32 fold GEMM ------------------------------
__global__ __launch_bounds__(256) void fold64(
    const float* __restrict__ A, int lda, int a_bx, int a_by,
    const float* __restrict__ B, int ldb, int b_bx, int b_by,
    float* __restrict__ C, int ldc, int c_bx, int c_by) {
  __shared__ float a_lds[64][132];
  __shared__ float b_lds[128][64];
  const int bx = blockIdx.x, by = blockIdx.y, tid = threadIdx.x;
  A += (size_t)bx * a_bx + (size_t)by * a_by;
  B += (size_t)bx * b_bx + (size_t)by * b_by;
  C += (size_t)bx * c_bx + (size_t)by * c_by;
  for (int i = tid; i < 64 * 32; i += 256) {
    int r = i >> 5, c4 = (i & 31) << 2;
    *(float4*)&a_lds[r][c4] = *(const float4*)&A[(size_t)r * lda + c4];
  }
  for (int i = tid; i < 128 * 16; i += 256) {
    int r = i >> 4, c4 = (i & 15) << 2;
    *(float4*)&b_lds[r][c4] = *(const float4*)&B[(size_t)r * ldb + c4];
  }
  __syncthreads();
  const int r = tid >> 2, l0 = (tid & 3) << 4;
  float acc[16] = {};
  for (int k = 0; k < 128; ++k) {
    float av = a_lds[r][k];
    const float* bp = &b_lds[k][l0];
#pragma unroll
    for (int j = 0; j < 16; ++j) acc[j] += av * bp[j];
  }
#pragma unroll
  for (int j4 = 0; j4 < 4; ++j4)
    *(float4*)&C[(size_t)r * ldc + l0 + j4 * 4] = *(float4*)&acc[j4 * 4];
}

// ---------- folded biases (coalesced) --------------------------------------
__global__ __launch_bounds__(256) void bias_prep(
    const float* __restrict__ bv, const float* __restrict__ Wcv,
    const float* __restrict__ bcv, const float* __restrict__ bd,
    const float* __restrict__ Wo, const float* __restrict__ bo,
    float* __restrict__ bias_vf, float* __restrict__ bias_out) {
  __shared__ float red[4][64];
  if (blockIdx.x == 32) {
    for (int e = threadIdx.x; e < 1024; e += 256) {
      int h = e >> 6, l = e & 63;
      float s = bcv[l];
      for (int j = 0; j < 128; ++j) s += bv[h * 128 + j] * Wcv[j * 64 + l];
      bias_vf[e] = s;
    }
  } else {
    int n0 = blockIdx.x * 64;
    int c = threadIdx.x & 63, g = threadIdx.x >> 6;
    float s = 0.f;
    for (int k = g * 512; k < (g + 1) * 512; ++k)
      s += bd[k & 127] * Wo[(size_t)k * 2048 + n0 + c];
    red[g][c] = s;
    __syncthreads();
    if (g == 0)
      bias_out[n0 + c] = red[0][c] + red[1][c] + red[2][c] + red[3][c] + bo[n0 + c];
  }
}

// ---------- fused QKV GEMM fp16, 128^2, BK=32, 3-buf counted-vmcnt, 8 waves
__global__ __launch_bounds__(512) void gemm_qkv(
    const u16* __restrict__ Af, const u16* __restrict__ Bf,
    u16* __restrict__ cQ, u16* __restrict__ cK, u16* __restrict__ cV,
    const float* __restrict__ bq, const float* __restrict__ bk,
    const float* __restrict__ bvf, int K) {
  __shared__ u16 s[3][2][128 * 32];  // 48KB -> 3 blocks/CU
  const int tid = threadIdx.x;
  const int lane = tid & 63;
  const int w = tid >> 6;
  const int wr = w >> 2, wc = w & 3;   // 2M x 4N waves
  const int l15 = lane & 15, lg = lane >> 4;
  const int row0 = blockIdx.y * 128, col0 = blockIdx.x * 128;

  const int sr = tid >> 2, sq = tid & 3;       // 128 rows x 4 slots
  const int sg = sq ^ ((sr >> 1) & 3);
  const size_t aoff = (size_t)(row0 + sr) * K + sg * 8;
  const size_t boff = (size_t)(col0 + sr) * K + sg * 8;
  const int ldst = tid * 16;

  f32x4 acc[4][2];
#pragma unroll
  for (int i2 = 0; i2 < 4; ++i2)
#pragma unroll
    for (int j2 = 0; j2 < 2; ++j2) acc[i2][j2] = (f32x4){0.f, 0.f, 0.f, 0.f};

  int fa[4], fb[2];
#pragma unroll
  for (int mi = 0; mi < 4; ++mi) {
    int ra = wr * 64 + mi * 16 + l15;
    fa[mi] = ra * 64 + ((lg ^ ((ra >> 1) & 3)) << 4);
  }
#pragma unroll
  for (int ni = 0; ni < 2; ++ni) {
    int rb = wc * 32 + ni * 16 + l15;
    fb[ni] = rb * 64 + ((lg ^ ((rb >> 1) & 3)) << 4);
  }

  const int NT = K >> 5;
  // prologue: stage buffers 0 and 1
  GL(Af + aoff,      (char*)&s[0][0][0] + ldst);
  GL(Bf + boff,      (char*)&s[0][1][0] + ldst);
  GL(Af + aoff + 32, (char*)&s[1][0][0] + ldst);
  GL(Bf + boff + 32, (char*)&s[1][1][0] + ldst);
  int cb = 0;
  for (int kt = 0; kt < NT; ++kt) {
    __builtin_amdgcn_sched_barrier(0);
    if (kt + 1 < NT) asm volatile("s_waitcnt vmcnt(2)" ::: "memory");
    else             asm volatile("s_waitcnt vmcnt(0)" ::: "memory");
    __builtin_amdgcn_s_barrier();   // raw: no implicit vmcnt(0) drain
    if (kt + 2 < NT) {
      int nb = cb - 1; if (nb < 0) nb = 2;   // (kt+2)%3
      GL(Af + aoff + (size_t)(kt + 2) * 32, (char*)&s[nb][0][0] + ldst);
      GL(Bf + boff + (size_t)(kt + 2) * 32, (char*)&s[nb][1][0] + ldst);
    }
    half8 a[4], b[2];
#pragma unroll
    for (int mi = 0; mi < 4; ++mi)
      a[mi] = *(const half8*)((const char*)&s[cb][0][0] + fa[mi]);
#pragma unroll
    for (int ni = 0; ni < 2; ++ni)
      b[ni] = *(const half8*)((const char*)&s[cb][1][0] + fb[ni]);
#pragma unroll
    for (int mi = 0; mi < 4; ++mi)
#pragma unroll
      for (int ni = 0; ni < 2; ++ni)
        acc[mi][ni] = __builtin_amdgcn_mfma_f32_16x16x32_f16(a[mi], b[ni], acc[mi][ni], 0, 0, 0);
    cb = cb + 1; if (cb == 3) cb = 0;
  }
  u16* Cp; const float* bp; int ldc, cl0;
  if (col0 < 2048)      { Cp = cQ; bp = bq;  ldc = 2048; cl0 = col0; }
  else if (col0 < 4096) { Cp = cK; bp = bk;  ldc = 2048; cl0 = col0 - 2048; }
  else                  { Cp = cV; bp = bvf; ldc = 1024; cl0 = col0 - 4096; }
#pragma unroll
  for (int ni = 0; ni < 2; ++ni) {
    int c = cl0 + wc * 32 + ni * 16 + l15;
    float bias = bp[c];
#pragma unroll
    for (int mi = 0; mi < 4; ++mi) {
      int rr = row0 + wr * 64 + mi * 16 + lg * 4;
#pragma unroll
      for (int r = 0; r < 4; ++r)
        Cp[(size_t)(rr + r) * ldc + c] = f16_rne(acc[mi][ni][r] + bias);
    }
  }
}

// ---------- fp16 MFMA GEMM (out-projection), BK=32, 3-buf, 8 waves ---------
__global__ __launch_bounds__(512) void gemm_f16(
    const u16* __restrict__ Af, const u16* __restrict__ Bf,
    const float* __restrict__ bias, float* __restrict__ C,
    int M, int N, int K) {
  __shared__ u16 s[3][2][128 * 32];
  const int tid = threadIdx.x;
  const int lane = tid & 63;
  const int w = tid >> 6;
  const int wr = w >> 2, wc = w & 3;
  const int l15 = lane & 15, lg = lane >> 4;
  const int row0 = blockIdx.y * 128, col0 = blockIdx.x * 128;

  const int sr = tid >> 2, sq = tid & 3;
  const int sg = sq ^ ((sr >> 1) & 3);
  const size_t aoff = (size_t)(row0 + sr) * K + sg * 8;
  const size_t boff = (size_t)(col0 + sr) * K + sg * 8;
  const int ldst = tid * 16;

  f32x4 acc[4][2];
#pragma unroll
  for (int i2 = 0; i2 < 4; ++i2)
#pragma unroll
    for (int j2 = 0; j2 < 2; ++j2) acc[i2][j2] = (f32x4){0.f, 0.f, 0.f, 0.f};

  int fa[4], fb[2];
#pragma unroll
  for (int mi = 0; mi < 4; ++mi) {
    int ra = wr * 64 + mi * 16 + l15;
    fa[mi] = ra * 64 + ((lg ^ ((ra >> 1) & 3)) << 4);
  }
#pragma unroll
  for (int ni = 0; ni < 2; ++ni) {
    int rb = wc * 32 + ni * 16 + l15;
    fb[ni] = rb * 64 + ((lg ^ ((rb >> 1) & 3)) << 4);
  }

  const int NT = K >> 5;
  GL(Af + aoff,      (char*)&s[0][0][0] + ldst);
  GL(Bf + boff,      (char*)&s[0][1][0] + ldst);
  GL(Af + aoff + 32, (char*)&s[1][0][0] + ldst);
  GL(Bf + boff + 32, (char*)&s[1][1][0] + ldst);
  int cb = 0;
  for (int kt = 0; kt < NT; ++kt) {
    __builtin_amdgcn_sched_barrier(0);
    if (kt + 1 < NT) asm volatile("s_waitcnt vmcnt(2)" ::: "memory");
    else             asm volatile("s_waitcnt vmcnt(0)" ::: "memory");
    __builtin_amdgcn_s_barrier();
    if (kt + 2 < NT) {
      int nb = cb - 1; if (nb < 0) nb = 2;
      GL(Af + aoff + (size_t)(kt + 2) * 32, (char*)&s[nb][0][0] + ldst);
      GL(Bf + boff + (size_t)(kt + 2) * 32, (char*)&s[nb][1][0] + ldst);
    }
    half8 a[4], b[2];
#pragma unroll
    for (int mi = 0; mi < 4; ++mi)
      a[mi] = *(const half8*)((const char*)&s[cb][0][0] + fa[mi]);
#pragma unroll
    for (int ni = 0; ni < 2; ++ni)
      b[ni] = *(const half8*)((const char*)&s[cb][1][0] + fb[ni]);
#pragma unroll
    for (int mi = 0; mi < 4; ++mi)
#pragma unroll
      for (int ni = 0; ni < 2; ++ni)
        acc[mi][ni] = __builtin_amdgcn_mfma_f32_16x16x32_f16(a[mi], b[ni], acc[mi][ni], 0, 0, 0);
    cb = cb + 1; if (cb == 3) cb = 0;
  }
#pragma unroll
  for (int ni = 0; ni < 2; ++ni) {
    int c = col0 + wc * 32 + ni * 16 + l15;
    float bv = bias[c];
#pragma unroll
    for (int mi = 0; mi < 4; ++mi) {
      int rr = row0 + wr * 64 + mi * 16 + lg * 4;
#pragma unroll
      for (int r = 0; r < 4; ++r)
        C[(size_t)(rr + r) * N + c] = acc[mi][ni][r] + bv;
    }
  }
}

// ---------- fused RoPE + latent compression via fp16 MFMA (paired Q/K) -----
__global__ __launch_bounds__(256) void compress_qk_mfma(
    const u16* __restrict__ srcQ, const u16* __restrict__ srcK,
    const u16* __restrict__ WcTq, const u16* __restrict__ WcTk,
    const float* __restrict__ bcq, const float* __restrict__ bck,
    const float* __restrict__ freqs,
    u16* __restrict__ dstQ, u16* __restrict__ dstK) {
  const u16* src = blockIdx.z ? srcK : srcQ;
  const u16* WcT = blockIdx.z ? WcTk : WcTq;
  const float* bc = blockIdx.z ? bck : bcq;
  u16* dst = blockIdx.z ? dstK : dstQ;
  __shared__ u16 q_lds[64 * 128];
  __shared__ u16 w_lds[64 * 128];
  const int tid = threadIdx.x;
  const int lane = tid & 63;
  const int w = tid >> 6;
  const int t0 = blockIdx.x * 64;
  const int bh = blockIdx.y, b = bh >> 4, h = bh & 15;

#pragma unroll
  for (int j = 0; j < 4; ++j) {
    int idx = tid + j * 256;
    int row = idx >> 4, slot = idx & 15;
    GL(WcT + (size_t)row * 128 + (size_t)(slot ^ (row & 7)) * 8,
       (char*)w_lds + idx * 16);
  }
  const int r = tid >> 2, seg = tid & 3;
  const u16* qp = src + ((size_t)(b * Tn + t0 + r)) * Dn + h * 128 + seg * 32;
  const float* fp = freqs + (size_t)(t0 + r) * 64 + seg * 16;
  float fr[16];
#pragma unroll
  for (int j = 0; j < 4; ++j) *(float4*)&fr[4 * j] = ((const float4*)fp)[j];
#pragma unroll
  for (int j = 0; j < 8; ++j) {
    ushort4v uv = *(const ushort4v*)(qp + 4 * j);
    float e0 = f16_to_f(uv[0]), e1 = f16_to_f(uv[1]);
    float e2 = f16_to_f(uv[2]), e3 = f16_to_f(uv[3]);
    float s0, c0, s1, c1;
    sincosf(fr[2 * j], &s0, &c0);
    sincosf(fr[2 * j + 1], &s1, &c1);
    ushort4v u;
    u[0] = f16_rne(e0 * c0 - e1 * s0);
    u[1] = f16_rne(e0 * s0 + e1 * c0);
    u[2] = f16_rne(e2 * c1 - e3 * s1);
    u[3] = f16_rne(e2 * s1 + e3 * c1);
    int slot = seg * 4 + (j & 3);
    *(ushort4v*)((char*)q_lds + r * 256 + ((slot ^ (r & 7)) << 4) + (j >> 2) * 8) = u;
  }
  __syncthreads();
  const int l15 = lane & 15, lg = lane >> 4;
  const int arow = w * 16 + l15;
  half8 af[4];
#pragma unroll
  for (int ks = 0; ks < 4; ++ks)
    af[ks] = *(const half8*)((const char*)q_lds + arow * 256 +
                             (((ks * 4 + lg) ^ (arow & 7)) << 4));
  f32x4 acc[4];
#pragma unroll
  for (int ni = 0; ni < 4; ++ni) acc[ni] = (f32x4){0.f, 0.f, 0.f, 0.f};
#pragma unroll
  for (int ni = 0; ni < 4; ++ni) {
    const int brow = ni * 16 + l15;
#pragma unroll
    for (int ks = 0; ks < 4; ++ks) {
      half8 bf = *(const half8*)((const char*)w_lds + brow * 256 +
                                 (((ks * 4 + lg) ^ (brow & 7)) << 4));
      acc[ni] = __builtin_amdgcn_mfma_f32_16x16x32_f16(af[ks], bf, acc[ni], 0, 0, 0);
    }
  }
  __syncthreads();
#pragma unroll
  for (int ni = 0; ni < 4; ++ni) {
    int lat = ni * 16 + l15;
    float bcv = bc[lat];
    int p = (lat & 32) + ((lat >> 2) & 3) * 8 + ((lat >> 4) & 1) * 4 + (lat & 3);
#pragma unroll
    for (int reg = 0; reg < 4; ++reg)
      q_lds[w * 1024 + (lg * 4 + reg) * 64 + p] = f16_rne(acc[ni][reg] + bcv);
  }
  __syncthreads();
#pragma unroll
  for (int j = 0; j < 2; ++j) {
    int idx = tid + j * 256;
    int row = idx >> 3, c8 = idx & 7;
    ushort8 val = *(const ushort8*)&q_lds[row * 64 + c8 * 8];
    *(ushort8*)(dst + ((size_t)bh * Tn + t0 + row) * 64 + c8 * 8) = val;
  }
}

// ---------- transpose v_lat [B*T][1024] f16 -> vlatT [bh][64][T-perm] f16 --
__global__ __launch_bounds__(256) void transpose_v(
    const u16* __restrict__ vlat, u16* __restrict__ vlatT) {
  __shared__ u16 o_lds[64][64];
  const int tid = threadIdx.x;
  const int t0 = blockIdx.x * 64;
  const int bh = blockIdx.y, b = bh >> 4, h = bh & 15;
  const int tt = tid >> 2, lseg = tid & 3;
  const u16* vp = vlat + (size_t)(b * Tn + t0 + tt) * 1024 + h * 64 + lseg * 16;
#pragma unroll
  for (int g = 0; g < 4; ++g) {
    ushort4v u = *(const ushort4v*)(vp + g * 4);
    *(ushort4v*)&o_lds[tt][lseg * 16 + ((g ^ (tt & 3)) << 2)] = u;
  }
  __syncthreads();
  const int lat = tid >> 2, tseg = tid & 3;
  const int tw = tseg >> 1, h4 = tseg & 1;
  u16 vals[16];
#pragma unroll
  for (int i = 0; i < 16; ++i)
    vals[i] = o_lds[tseg * 16 + i][lat ^ ((i & 3) << 2)];
  u16* dp = vlatT + ((size_t)bh * 64 + lat) * Tn + t0 + tw * 32 + h4 * 4;
#pragma unroll
  for (int g = 0; g < 4; ++g) {
    ushort4v u = {vals[g * 4 + 0], vals[g * 4 + 1], vals[g * 4 + 2], vals[g * 4 + 3]};
    *(ushort4v*)(dp + g * 8) = u;
  }
}

// ---------- MFMA flash attention, QBLK=64, fp16, XCD-chunked ---------------
__global__ __launch_bounds__(256) void attn_mfma(
    const u16* __restrict__ qlat, const u16* __restrict__ klat,
    const u16* __restrict__ vlatT, u16* __restrict__ oh) {
  __shared__ u16 Ks[64 * 72];
  __shared__ u16 Vs[64 * 72];
  __shared__ u16 Os[64][72];
  const int tid = threadIdx.x;
  const int lane = tid & 63;
  const int w = tid >> 6;
  const int lin = (int)(blockIdx.x + blockIdx.y * gridDim.x);
  const int nchunk = (int)(gridDim.x * gridDim.y) >> 3;
  const int swz = (lin & 7) * nchunk + (lin >> 3);
  const int bh = swz >> 5, b = bh >> 4, h = bh & 15;
  const int q0 = (31 - (swz & 31)) * 64;
  const int qw = q0 + w * 16;
  const u16* ql = qlat + (size_t)bh * Tn * 64;
  const u16* kl = klat + (size_t)bh * Tn * 64;
  const u16* vt = vlatT + (size_t)bh * 64 * Tn;
  const int l15 = lane & 15, lg = lane >> 4;

  half8 qf[2];
#pragma unroll
  for (int ks = 0; ks < 2; ++ks)
    qf[ks] = *(const half8*)(const void*)(ql + (size_t)(qw + l15) * 64 + (ks * 4 + lg) * 8);

  f32x4 accO[4];
#pragma unroll
  for (int mi = 0; mi < 4; ++mi) accO[mi] = (f32x4){0.f, 0.f, 0.f, 0.f};
  float mrow = -1e30f, lrow = 0.f;

  const int srow = tid >> 2, spair = tid & 3;
  u16* ksw = &Ks[srow * 72 + spair * 16];
  u16* vsw = &Vs[srow * 72 + spair * 16];
  const u16* kgp = kl + (size_t)srow * 64 + spair * 16;
  const u16* vgp = vt + (size_t)srow * Tn + spair * 16;

  ushort8 kr0 = *(const ushort8*)(kgp);
  ushort8 kr1 = *(const ushort8*)(kgp + 8);
  ushort8 vr0 = *(const ushort8*)(vgp);
  ushort8 vr1 = *(const ushort8*)(vgp + 8);

  const int ntiles = q0 / 64 + 1;
  for (int kt = 0; kt < ntiles; ++kt) {
    const int k0 = kt * 64;
    __syncthreads();
    *(ushort8*)ksw       = kr0;
    *(ushort8*)(ksw + 8) = kr1;
    *(ushort8*)vsw       = vr0;
    *(ushort8*)(vsw + 8) = vr1;
    __syncthreads();
    {
      int kn = k0 + 64; kn = kn > (int)Tn - 64 ? (int)Tn - 64 : kn;
      kr0 = *(const ushort8*)(kgp + (size_t)kn * 64);
      kr1 = *(const ushort8*)(kgp + (size_t)kn * 64 + 8);
      vr0 = *(const ushort8*)(vgp + kn);
      vr1 = *(const ushort8*)(vgp + kn + 8);
    }
    f32x4 s4[4];
#pragma unroll
    for (int mi = 0; mi < 4; ++mi) s4[mi] = (f32x4){0.f, 0.f, 0.f, 0.f};
    __builtin_amdgcn_s_setprio(1);
#pragma unroll
    for (int ks = 0; ks < 2; ++ks) {
      half8 kf[4];
#pragma unroll
      for (int mi = 0; mi < 4; ++mi)
        kf[mi] = *(const half8*)(const void*)&Ks[(mi * 16 + l15) * 72 + (ks * 4 + lg) * 8];
#pragma unroll
      for (int mi = 0; mi < 4; ++mi)
        s4[mi] = __builtin_amdgcn_mfma_f32_16x16x32_f16(kf[mi], qf[ks], s4[mi], 0, 0, 0);
    }
    __builtin_amdgcn_s_setprio(0);
    const bool needmask = (kt == ntiles - 1);
    const int qidx = qw + l15;
    float p[4][4];
    float tmax = -1e30f;
#pragma unroll
    for (int mi = 0; mi < 4; ++mi)
#pragma unroll
      for (int rr = 0; rr < 4; ++rr) {
        float v = s4[mi][rr] * SL2E;
        if (needmask && (k0 + mi * 16 + lg * 4 + rr > qidx)) v = -1e30f;
        p[mi][rr] = v;
        tmax = fmaxf(tmax, v);
      }
    tmax = fmaxf(tmax, __shfl_xor(tmax, 16));
    tmax = fmaxf(tmax, __shfl_xor(tmax, 32));
    if (!__all(tmax - mrow <= 8.f)) {
      float mnew = fmaxf(mrow, tmax);
      float alpha = exp2f(mrow - mnew);
      lrow *= alpha;
#pragma unroll
      for (int mi = 0; mi < 4; ++mi)
#pragma unroll
        for (int rr = 0; rr < 4; ++rr) accO[mi][rr] *= alpha;
      mrow = mnew;
    }
    float psum = 0.f;
    u16 ph[4][4];
#pragma unroll
    for (int mi = 0; mi < 4; ++mi)
#pragma unroll
      for (int rr = 0; rr < 4; ++rr) {
        float e = exp2f(p[mi][rr] - mrow);
        u16 hb = f16_rne(e);
        psum += f16_to_f(hb);
        ph[mi][rr] = hb;
      }
    psum += __shfl_xor(psum, 16);
    psum += __shfl_xor(psum, 32);
    lrow += psum;
    ushort8 pf[2];
#pragma unroll
    for (int ks = 0; ks < 2; ++ks) {
      ushort8 f;
#pragma unroll
      for (int rr = 0; rr < 4; ++rr) {
        f[rr]     = ph[2 * ks][rr];
        f[4 + rr] = ph[2 * ks + 1][rr];
      }
      pf[ks] = f;
    }
    __builtin_amdgcn_s_setprio(1);
#pragma unroll
    for (int ks = 0; ks < 2; ++ks) {
      half8 vf[4];
#pragma unroll
      for (int mi = 0; mi < 4; ++mi)
        vf[mi] = *(const half8*)(const void*)&Vs[(mi * 16 + l15) * 72 + (ks * 4 + lg) * 8];
#pragma unroll
      for (int mi = 0; mi < 4; ++mi)
        accO[mi] = __builtin_amdgcn_mfma_f32_16x16x32_f16(vf[mi], *(const half8*)&pf[ks], accO[mi], 0, 0, 0);
    }
    __builtin_amdgcn_s_setprio(0);
  }
  __syncthreads();
  {
    float inv = 1.f / lrow;
    int qloc = w * 16 + l15;
#pragma unroll
    for (int mi = 0; mi < 4; ++mi) {
      int pbase = (mi >> 1) * 32 + lg * 8 + (mi & 1) * 4;
      ushort4v u;
#pragma unroll
      for (int rr = 0; rr < 4; ++rr) u[rr] = f16_rne(accO[mi][rr] * inv);
      *(ushort4v*)&Os[qloc][pbase] = u;
    }
  }
  __syncthreads();
  {
    int rid = tid >> 2, seg = tid & 3;
    u16* dstp = oh + ((size_t)(b * Tn + q0 + rid)) * 1024 + h * 64 + seg * 16;
#pragma unroll
    for (int g = 0; g < 2; ++g)
      *(ushort8*)(dstp + g * 8) = *(const ushort8*)&Os[rid][seg * 16 + g * 8];
  }
}

// ---------------------------------------------------------------------------
extern "C" void kernel_launch(void* const* d_in, const int* in_sizes, int n_in,
                              void* d_out, int out_size, void* d_ws, size_t ws_size,
                              hipStream_t stream) {
  const float* x     = (const float*)d_in[0];
  const float* freqs = (const float*)d_in[1];
  const float* Wq  = (const float*)d_in[3];  const float* bq  = (const float*)d_in[4];
  const float* Wk  = (const float*)d_in[5];  const float* bk  = (const float*)d_in[6];
  const float* Wv  = (const float*)d_in[7];  const float* bv  = (const float*)d_in[8];
  const float* Wo  = (const float*)d_in[9];  const float* bo  = (const float*)d_in[10];
  const float* Wcq = (const float*)d_in[11]; const float* bcq = (const float*)d_in[12];
  const float* Wck = (const float*)d_in[13]; const float* bck = (const float*)d_in[14];
  const float* Wcv = (const float*)d_in[15]; const float* bcv = (const float*)d_in[16];
  const float* Wd  = (const float*)d_in[17]; const float* bd  = (const float*)d_in[18];
  float* out = (float*)d_out;

  const size_t BT = (size_t)Bsz * Tn;          // 4096
  const size_t nQ = BT * Dn;                   // 8.39M
  const size_t nL = BT * Hn * Ln;              // 4.19M
  const size_t nWT = (size_t)5120 * 2048;      // 10.49M

  char* ws = (char*)d_ws;
  u16* xf   = (u16*)ws;
  u16* WTf  = xf + nQ;
  float* Wvf = (float*)(WTf + nWT);
  u16* Qh   = (u16*)(Wvf + (size_t)2048 * 1024);
  u16* Kh   = Qh + nQ;
  u16* vlat = Kh + nQ;
  float* bias_vf  = (float*)(vlat + (size_t)4096 * 1024);
  float* bias_out = bias_vf + 1024;
  u16* qlat  = (u16*)(bias_out + 2048);
  u16* klat  = qlat + nL;
  u16* vlatT = klat + nL;
  u16* oh = (u16*)(vlatT + nL);                        // [4096][1024] f16
  float* Wdo = (float*)(oh + (size_t)4096 * 1024);
  u16* WdoT = (u16*)(Wdo + (size_t)1024 * 2048);
  u16* WcqT = WdoT + (size_t)2048 * 1024;
  u16* WckT = WcqT + (size_t)64 * 128;

  dim3 blk(256);
  int nblkA = (int)(nQ / 8);

  // stage 1: operand prep
  split_h<<<(nblkA + 255) / 256, blk, 0, stream>>>(x, xf, nblkA, Dn);
  fold64<<<dim3(32, 16), blk, 0, stream>>>(Wv, 2048, 64 * 2048, 128,
                                           Wcv, 64, 0, 0,
                                           Wvf, 1024, 64 * 1024, 64);
  transpose_h2<<<dim3(64, 64, 2), blk, 0, stream>>>(Wq, Wk, WTf,
                                                    WTf + (size_t)2048 * 2048, 2048, 2048);
  transpose_h2<<<dim3(64, 32, 1), blk, 0, stream>>>(Wvf, Wvf, WTf + (size_t)4096 * 2048,
                                                    WTf + (size_t)4096 * 2048, 2048, 1024);
  transpose_h2<<<dim3(4, 2, 2), blk, 0, stream>>>(Wcq, Wck, WcqT, WckT, 128, 64);
  bias_prep<<<33, blk, 0, stream>>>(bv, Wcv, bcv, bd, Wo, bo, bias_vf, bias_out);

  // stage 2: fused Q/K/V-latent GEMM (N=5120, fp16, BK=32, 3-buf pipeline)
  gemm_qkv<<<dim3(40, 32), dim3(512), 0, stream>>>(xf, WTf, Qh, Kh, vlat,
                                                   bq, bk, bias_vf, 2048);

  // stage 3: latent Q/K (RoPE fused, MFMA, paired) + V transpose
  compress_qk_mfma<<<dim3(Tn / 64, Bsz * Hn, 2), blk, 0, stream>>>(
      Qh, Kh, WcqT, WckT, bcq, bck, freqs, qlat, klat);
  transpose_v<<<dim3(Tn / 64, Bsz * Hn), blk, 0, stream>>>(vlat, vlatT);

  // stage 4: attention (QBLK=64, fp16 MFMA, defer-max, XCD-chunked, fused oh)
  attn_mfma<<<dim3(Tn / 64, Bsz * Hn), blk, 0, stream>>>(qlat, klat, vlatT, oh);

  // stage 5: folded decompress+output projection (BK=32, 3-buf pipeline)
  fold64<<<dim3(32, 16), blk, 0, stream>>>(Wd, 128, 0, 0,
                                           Wo, 2048, 64, 128 * 2048,
                                           Wdo, 2048, 64, 64 * 2048);
  transpose_h2<<<dim3(32, 64, 1), blk, 0, stream>>>(Wdo, Wdo, WdoT, WdoT, 1024, 2048);
  gemm_f16<<<dim3(16, 32), dim3(512), 0, stream>>>(oh, WdoT, bias_out, out, (int)BT, 2048, 1024);
}

// Round 16
// 325.290 us; speedup vs baseline: 1.0239x; 1.0239x over previous
//
#include <hip/hip_runtime.h>
#include <hip/hip_bf16.h>

static constexpr int Bsz = 2;
static constexpr int Tn  = 2048;
static constexpr int Dn  = 2048;
static constexpr int Hn  = 16;
static constexpr int Ln  = 64;
static constexpr int Hd  = 128;
static constexpr float SL2E = 0.125f * 1.44269504088896f;  // SCALE * log2(e)

typedef short short8 __attribute__((ext_vector_type(8)));
typedef float f32x4 __attribute__((ext_vector_type(4)));
typedef unsigned short ushort8 __attribute__((ext_vector_type(8)));
typedef unsigned short ushort4v __attribute__((ext_vector_type(4)));
typedef _Float16 half8 __attribute__((ext_vector_type(8)));
typedef unsigned short u16;

__device__ inline u16 f16_rne(float f) {
  _Float16 h = (_Float16)f;  // RNE
  union { _Float16 h; u16 u; } x; x.h = h;
  return x.u;
}
__device__ inline float f16_to_f(u16 u) {
  union { u16 u; _Float16 h; } x; x.u = u;
  return (float)x.h;
}

#define GL(g, l) __builtin_amdgcn_global_load_lds(                     \
    (const __attribute__((address_space(1))) void*)(g),                \
    (__attribute__((address_space(3))) void*)(l), 16, 0, 0)

// ---------- fp32 -> fp16 with per-32 K-window permutation ------------------
__global__ void split_h(const float* __restrict__ A, u16* __restrict__ O,
                        int nblk, int Kd) {
  int b = blockIdx.x * 256 + threadIdx.x;
  if (b >= nblk) return;
  int perRow = Kd >> 3;
  int m = b / perRow, gb = b - m * perRow;
  int w = gb >> 2, g = gb & 3;
  const float* src = A + (size_t)m * Kd + (w << 5) + (g << 2);
  float4 v0 = *(const float4*)src;
  float4 v1 = *(const float4*)(src + 16);
  float e[8] = {v0.x, v0.y, v0.z, v0.w, v1.x, v1.y, v1.z, v1.w};
  ushort8 o;
#pragma unroll
  for (int j = 0; j < 8; ++j) o[j] = f16_rne(e[j]);
  *(ushort8*)(O + (size_t)b * 8) = o;
}

// ---------- transpose W[K][N] -> WT[N][K] fp16, K-permuted (paired) --------
__global__ __launch_bounds__(256) void transpose_h2(
    const float* __restrict__ W0, const float* __restrict__ W1,
    u16* __restrict__ T0, u16* __restrict__ T1, int Kd, int Nd) {
  const float* W = blockIdx.z ? W1 : W0;
  u16* Th = blockIdx.z ? T1 : T0;
  __shared__ float t[32][33];
  int k0 = blockIdx.x * 32, n0 = blockIdx.y * 32;
  int i = threadIdx.x;
  {
    int kk = i >> 3, nn = (i & 7) << 2;
    float4 v = *(const float4*)&W[(size_t)(k0 + kk) * Nd + n0 + nn];
    t[kk][nn] = v.x; t[kk][nn + 1] = v.y; t[kk][nn + 2] = v.z; t[kk][nn + 3] = v.w;
  }
  __syncthreads();
  int n = i >> 3, t2 = i & 7;
  int g = t2 >> 1, h = t2 & 1;
  int kbase = h * 16 + g * 4;
  ushort4v o;
#pragma unroll
  for (int j = 0; j < 4; ++j) o[j] = f16_rne(t[kbase + j][n]);
  *(ushort4v*)(Th + (size_t)(n0 + n) * Kd + k0 + t2 * 4) = o;
}

// ---------- generic 64x64-tile fp32 fold GEMM ------------------------------
__global__ __launch_bounds__(256) void fold64(
    const float* __restrict__ A, int lda, int a_bx, int a_by,
    const float* __restrict__ B, int ldb, int b_bx, int b_by,
    float* __restrict__ C, int ldc, int c_bx, int c_by) {
  __shared__ float a_lds[64][132];
  __shared__ float b_lds[128][64];
  const int bx = blockIdx.x, by = blockIdx.y, tid = threadIdx.x;
  A += (size_t)bx * a_bx + (size_t)by * a_by;
  B += (size_t)bx * b_bx + (size_t)by * b_by;
  C += (size_t)bx * c_bx + (size_t)by * c_by;
  for (int i = tid; i < 64 * 32; i += 256) {
    int r = i >> 5, c4 = (i & 31) << 2;
    *(float4*)&a_lds[r][c4] = *(const float4*)&A[(size_t)r * lda + c4];
  }
  for (int i = tid; i < 128 * 16; i += 256) {
    int r = i >> 4, c4 = (i & 15) << 2;
    *(float4*)&b_lds[r][c4] = *(const float4*)&B[(size_t)r * ldb + c4];
  }
  __syncthreads();
  const int r = tid >> 2, l0 = (tid & 3) << 4;
  float acc[16] = {};
  for (int k = 0; k < 128; ++k) {
    float av = a_lds[r][k];
    const float* bp = &b_lds[k][l0];
#pragma unroll
    for (int j = 0; j < 16; ++j) acc[j] += av * bp[j];
  }
#pragma unroll
  for (int j4 = 0; j4 < 4; ++j4)
    *(float4*)&C[(size_t)r * ldc + l0 + j4 * 4] = *(float4*)&acc[j4 * 4];
}

// ---------- folded biases (coalesced) --------------------------------------
__global__ __launch_bounds__(256) void bias_prep(
    const float* __restrict__ bv, const float* __restrict__ Wcv,
    const float* __restrict__ bcv, const float* __restrict__ bd,
    const float* __restrict__ Wo, const float* __restrict__ bo,
    float* __restrict__ bias_vf, float* __restrict__ bias_out) {
  __shared__ float red[4][64];
  if (blockIdx.x == 32) {
    for (int e = threadIdx.x; e < 1024; e += 256) {
      int h = e >> 6, l = e & 63;
      float s = bcv[l];
      for (int j = 0; j < 128; ++j) s += bv[h * 128 + j] * Wcv[j * 64 + l];
      bias_vf[e] = s;
    }
  } else {
    int n0 = blockIdx.x * 64;
    int c = threadIdx.x & 63, g = threadIdx.x >> 6;
    float s = 0.f;
    for (int k = g * 512; k < (g + 1) * 512; ++k)
      s += bd[k & 127] * Wo[(size_t)k * 2048 + n0 + c];
    red[g][c] = s;
    __syncthreads();
    if (g == 0)
      bias_out[n0 + c] = red[0][c] + red[1][c] + red[2][c] + red[3][c] + bo[n0 + c];
  }
}

// ---------- fused QKV GEMM fp16, 128^2 tile, BK=64, 8 waves (R14 best) -----
__global__ __launch_bounds__(512) void gemm_qkv(
    const u16* __restrict__ Af, const u16* __restrict__ Bf,
    u16* __restrict__ cQ, u16* __restrict__ cK, u16* __restrict__ cV,
    const float* __restrict__ bq, const float* __restrict__ bk,
    const float* __restrict__ bvf, int K) {
  __shared__ u16 s[2][2][128 * 64];  // [buf][A/B], 16KB each -> 64KB
  const int tid = threadIdx.x;
  const int lane = tid & 63;
  const int w = tid >> 6;            // 0..7
  const int wr = w >> 2, wc = w & 3; // 2M x 4N wave grid
  const int l15 = lane & 15, lg = lane >> 4;
  const int row0 = blockIdx.y * 128, col0 = blockIdx.x * 128;

  const int sr = tid >> 3, sq = tid & 7;   // sr 0..63
  const int sg = sq ^ (sr & 7);
  size_t aoff[2], boff[2];
#pragma unroll
  for (int j = 0; j < 2; ++j) {
    aoff[j] = (size_t)(row0 + j * 64 + sr) * K + sg * 8;
    boff[j] = (size_t)(col0 + j * 64 + sr) * K + sg * 8;
  }

  f32x4 acc[4][2];
#pragma unroll
  for (int i2 = 0; i2 < 4; ++i2)
#pragma unroll
    for (int j2 = 0; j2 < 2; ++j2) acc[i2][j2] = (f32x4){0.f, 0.f, 0.f, 0.f};

  int fa[4][2], fb[2][2];
#pragma unroll
  for (int mi = 0; mi < 4; ++mi) {
    int ra = wr * 64 + mi * 16 + l15;
#pragma unroll
    for (int kk = 0; kk < 2; ++kk)
      fa[mi][kk] = ra * 128 + (((kk * 4 + lg) ^ (ra & 7)) << 4);
  }
#pragma unroll
  for (int ni = 0; ni < 2; ++ni) {
    int rb = wc * 32 + ni * 16 + l15;
#pragma unroll
    for (int kk = 0; kk < 2; ++kk)
      fb[ni][kk] = 16384 + rb * 128 + (((kk * 4 + lg) ^ (rb & 7)) << 4);
  }

#pragma unroll
  for (int j = 0; j < 2; ++j) {
    GL(Af + aoff[j], (char*)&s[0][0][0] + j * 8192 + tid * 16);
    GL(Bf + boff[j], (char*)&s[0][1][0] + j * 8192 + tid * 16);
  }
  int cur = 0;
  for (int k0 = 0; k0 < K; k0 += 64) {
    __syncthreads();
    if (k0 + 64 < K) {
      const int nb = cur ^ 1;
#pragma unroll
      for (int j = 0; j < 2; ++j) {
        GL(Af + aoff[j] + k0 + 64, (char*)&s[nb][0][0] + j * 8192 + tid * 16);
        GL(Bf + boff[j] + k0 + 64, (char*)&s[nb][1][0] + j * 8192 + tid * 16);
      }
    }
#pragma unroll
    for (int kk = 0; kk < 2; ++kk) {
      half8 a[4], b[2];
#pragma unroll
      for (int mi = 0; mi < 4; ++mi)
        a[mi] = *(const half8*)((const char*)&s[cur][0][0] + fa[mi][kk]);
#pragma unroll
      for (int ni = 0; ni < 2; ++ni)
        b[ni] = *(const half8*)((const char*)&s[cur][0][0] + fb[ni][kk]);
#pragma unroll
      for (int mi = 0; mi < 4; ++mi)
#pragma unroll
        for (int ni = 0; ni < 2; ++ni)
          acc[mi][ni] = __builtin_amdgcn_mfma_f32_16x16x32_f16(a[mi], b[ni], acc[mi][ni], 0, 0, 0);
    }
    cur ^= 1;
  }
  u16* Cp; const float* bp; int ldc, cl0;
  if (col0 < 2048)      { Cp = cQ; bp = bq;  ldc = 2048; cl0 = col0; }
  else if (col0 < 4096) { Cp = cK; bp = bk;  ldc = 2048; cl0 = col0 - 2048; }
  else                  { Cp = cV; bp = bvf; ldc = 1024; cl0 = col0 - 4096; }
#pragma unroll
  for (int ni = 0; ni < 2; ++ni) {
    int c = cl0 + wc * 32 + ni * 16 + l15;
    float bias = bp[c];
#pragma unroll
    for (int mi = 0; mi < 4; ++mi) {
      int rr = row0 + wr * 64 + mi * 16 + lg * 4;
#pragma unroll
      for (int r = 0; r < 4; ++r)
        Cp[(size_t)(rr + r) * ldc + c] = f16_rne(acc[mi][ni][r] + bias);
    }
  }
}

// ---------- fp16 MFMA GEMM (final out-projection), BK=64, 8 waves ----------
__global__ __launch_bounds__(512) void gemm_f16(
    const u16* __restrict__ Af, const u16* __restrict__ Bf,
    const float* __restrict__ bias, float* __restrict__ C,
    int M, int N, int K) {
  __shared__ u16 s[2][2][128 * 64];
  const int tid = threadIdx.x;
  const int lane = tid & 63;
  const int w = tid >> 6;
  const int wr = w >> 2, wc = w & 3;
  const int l15 = lane & 15, lg = lane >> 4;
  const int row0 = blockIdx.y * 128, col0 = blockIdx.x * 128;

  const int sr = tid >> 3, sq = tid & 7;
  const int sg = sq ^ (sr & 7);
  size_t aoff[2], boff[2];
#pragma unroll
  for (int j = 0; j < 2; ++j) {
    aoff[j] = (size_t)(row0 + j * 64 + sr) * K + sg * 8;
    boff[j] = (size_t)(col0 + j * 64 + sr) * K + sg * 8;
  }

  f32x4 acc[4][2];
#pragma unroll
  for (int i2 = 0; i2 < 4; ++i2)
#pragma unroll
    for (int j2 = 0; j2 < 2; ++j2) acc[i2][j2] = (f32x4){0.f, 0.f, 0.f, 0.f};

  int fa[4][2], fb[2][2];
#pragma unroll
  for (int mi = 0; mi < 4; ++mi) {
    int ra = wr * 64 + mi * 16 + l15;
#pragma unroll
    for (int kk = 0; kk < 2; ++kk)
      fa[mi][kk] = ra * 128 + (((kk * 4 + lg) ^ (ra & 7)) << 4);
  }
#pragma unroll
  for (int ni = 0; ni < 2; ++ni) {
    int rb = wc * 32 + ni * 16 + l15;
#pragma unroll
    for (int kk = 0; kk < 2; ++kk)
      fb[ni][kk] = 16384 + rb * 128 + (((kk * 4 + lg) ^ (rb & 7)) << 4);
  }

#pragma unroll
  for (int j = 0; j < 2; ++j) {
    GL(Af + aoff[j], (char*)&s[0][0][0] + j * 8192 + tid * 16);
    GL(Bf + boff[j], (char*)&s[0][1][0] + j * 8192 + tid * 16);
  }
  int cur = 0;
  for (int k0 = 0; k0 < K; k0 += 64) {
    __syncthreads();
    if (k0 + 64 < K) {
      const int nb = cur ^ 1;
#pragma unroll
      for (int j = 0; j < 2; ++j) {
        GL(Af + aoff[j] + k0 + 64, (char*)&s[nb][0][0] + j * 8192 + tid * 16);
        GL(Bf + boff[j] + k0 + 64, (char*)&s[nb][1][0] + j * 8192 + tid * 16);
      }
    }
#pragma unroll
    for (int kk = 0; kk < 2; ++kk) {
      half8 a[4], b[2];
#pragma unroll
      for (int mi = 0; mi < 4; ++mi)
        a[mi] = *(const half8*)((const char*)&s[cur][0][0] + fa[mi][kk]);
#pragma unroll
      for (int ni = 0; ni < 2; ++ni)
        b[ni] = *(const half8*)((const char*)&s[cur][0][0] + fb[ni][kk]);
#pragma unroll
      for (int mi = 0; mi < 4; ++mi)
#pragma unroll
        for (int ni = 0; ni < 2; ++ni)
          acc[mi][ni] = __builtin_amdgcn_mfma_f32_16x16x32_f16(a[mi], b[ni], acc[mi][ni], 0, 0, 0);
    }
    cur ^= 1;
  }
#pragma unroll
  for (int ni = 0; ni < 2; ++ni) {
    int c = col0 + wc * 32 + ni * 16 + l15;
    float bv = bias[c];
#pragma unroll
    for (int mi = 0; mi < 4; ++mi) {
      int rr = row0 + wr * 64 + mi * 16 + lg * 4;
#pragma unroll
      for (int r = 0; r < 4; ++r)
        C[(size_t)(rr + r) * N + c] = acc[mi][ni][r] + bv;
    }
  }
}

// ---------- fused RoPE + latent compression via fp16 MFMA (paired Q/K) -----
__global__ __launch_bounds__(256) void compress_qk_mfma(
    const u16* __restrict__ srcQ, const u16* __restrict__ srcK,
    const u16* __restrict__ WcTq, const u16* __restrict__ WcTk,
    const float* __restrict__ bcq, const float* __restrict__ bck,
    const float* __restrict__ freqs,
    u16* __restrict__ dstQ, u16* __restrict__ dstK) {
  const u16* src = blockIdx.z ? srcK : srcQ;
  const u16* WcT = blockIdx.z ? WcTk : WcTq;
  const float* bc = blockIdx.z ? bck : bcq;
  u16* dst = blockIdx.z ? dstK : dstQ;
  __shared__ u16 q_lds[64 * 128];
  __shared__ u16 w_lds[64 * 128];
  const int tid = threadIdx.x;
  const int lane = tid & 63;
  const int w = tid >> 6;
  const int t0 = blockIdx.x * 64;
  const int bh = blockIdx.y, b = bh >> 4, h = bh & 15;

#pragma unroll
  for (int j = 0; j < 4; ++j) {
    int idx = tid + j * 256;
    int row = idx >> 4, slot = idx & 15;
    GL(WcT + (size_t)row * 128 + (size_t)(slot ^ (row & 7)) * 8,
       (char*)w_lds + idx * 16);
  }
  const int r = tid >> 2, seg = tid & 3;
  const u16* qp = src + ((size_t)(b * Tn + t0 + r)) * Dn + h * 128 + seg * 32;
  const float* fp = freqs + (size_t)(t0 + r) * 64 + seg * 16;
  float fr[16];
#pragma unroll
  for (int j = 0; j < 4; ++j) *(float4*)&fr[4 * j] = ((const float4*)fp)[j];
#pragma unroll
  for (int j = 0; j < 8; ++j) {
    ushort4v uv = *(const ushort4v*)(qp + 4 * j);
    float e0 = f16_to_f(uv[0]), e1 = f16_to_f(uv[1]);
    float e2 = f16_to_f(uv[2]), e3 = f16_to_f(uv[3]);
    float s0, c0, s1, c1;
    sincosf(fr[2 * j], &s0, &c0);
    sincosf(fr[2 * j + 1], &s1, &c1);
    ushort4v u;
    u[0] = f16_rne(e0 * c0 - e1 * s0);
    u[1] = f16_rne(e0 * s0 + e1 * c0);
    u[2] = f16_rne(e2 * c1 - e3 * s1);
    u[3] = f16_rne(e2 * s1 + e3 * c1);
    int slot = seg * 4 + (j & 3);
    *(ushort4v*)((char*)q_lds + r * 256 + ((slot ^ (r & 7)) << 4) + (j >> 2) * 8) = u;
  }
  __syncthreads();
  const int l15 = lane & 15, lg = lane >> 4;
  const int arow = w * 16 + l15;
  half8 af[4];
#pragma unroll
  for (int ks = 0; ks < 4; ++ks)
    af[ks] = *(const half8*)((const char*)q_lds + arow * 256 +
                             (((ks * 4 + lg) ^ (arow & 7)) << 4));
  f32x4 acc[4];
#pragma unroll
  for (int ni = 0; ni < 4; ++ni) acc[ni] = (f32x4){0.f, 0.f, 0.f, 0.f};
#pragma unroll
  for (int ni = 0; ni < 4; ++ni) {
    const int brow = ni * 16 + l15;
#pragma unroll
    for (int ks = 0; ks < 4; ++ks) {
      half8 bf = *(const half8*)((const char*)w_lds + brow * 256 +
                                 (((ks * 4 + lg) ^ (brow & 7)) << 4));
      acc[ni] = __builtin_amdgcn_mfma_f32_16x16x32_f16(af[ks], bf, acc[ni], 0, 0, 0);
    }
  }
  __syncthreads();
#pragma unroll
  for (int ni = 0; ni < 4; ++ni) {
    int lat = ni * 16 + l15;
    float bcv = bc[lat];
    int p = (lat & 32) + ((lat >> 2) & 3) * 8 + ((lat >> 4) & 1) * 4 + (lat & 3);
#pragma unroll
    for (int reg = 0; reg < 4; ++reg)
      q_lds[w * 1024 + (lg * 4 + reg) * 64 + p] = f16_rne(acc[ni][reg] + bcv);
  }
  __syncthreads();
#pragma unroll
  for (int j = 0; j < 2; ++j) {
    int idx = tid + j * 256;
    int row = idx >> 3, c8 = idx & 7;
    ushort8 val = *(const ushort8*)&q_lds[row * 64 + c8 * 8];
    *(ushort8*)(dst + ((size_t)bh * Tn + t0 + row) * 64 + c8 * 8) = val;
  }
}

// ---------- transpose v_lat [B*T][1024] f16 -> vlatT [bh][64][T-perm] f16 --
__global__ __launch_bounds__(256) void transpose_v(
    const u16* __restrict__ vlat, u16* __restrict__ vlatT) {
  __shared__ u16 o_lds[64][64];
  const int tid = threadIdx.x;
  const int t0 = blockIdx.x * 64;
  const int bh = blockIdx.y, b = bh >> 4, h = bh & 15;
  const int tt = tid >> 2, lseg = tid & 3;
  const u16* vp = vlat + (size_t)(b * Tn + t0 + tt) * 1024 + h * 64 + lseg * 16;
#pragma unroll
  for (int g = 0; g < 4; ++g) {
    ushort4v u = *(const ushort4v*)(vp + g * 4);
    *(ushort4v*)&o_lds[tt][lseg * 16 + ((g ^ (tt & 3)) << 2)] = u;
  }
  __syncthreads();
  const int lat = tid >> 2, tseg = tid & 3;
  const int tw = tseg >> 1, h4 = tseg & 1;
  u16 vals[16];
#pragma unroll
  for (int i = 0; i < 16; ++i)
    vals[i] = o_lds[tseg * 16 + i][lat ^ ((i & 3) << 2)];
  u16* dp = vlatT + ((size_t)bh * 64 + lat) * Tn + t0 + tw * 32 + h4 * 4;
#pragma unroll
  for (int g = 0; g < 4; ++g) {
    ushort4v u = {vals[g * 4 + 0], vals[g * 4 + 1], vals[g * 4 + 2], vals[g * 4 + 3]};
    *(ushort4v*)(dp + g * 8) = u;
  }
}

// ---------- MFMA flash attention, QBLK=64, fp16, XCD-chunked, Os->Ks alias -
__global__ __launch_bounds__(256) void attn_mfma(
    const u16* __restrict__ qlat, const u16* __restrict__ klat,
    const u16* __restrict__ vlatT, u16* __restrict__ oh) {
  __shared__ u16 Ks[64 * 72];
  __shared__ u16 Vs[64 * 72];
  u16(*Os)[72] = (u16(*)[72])Ks;   // alias: Ks dead after main loop
  const int tid = threadIdx.x;
  const int lane = tid & 63;
  const int w = tid >> 6;
  const int lin = (int)(blockIdx.x + blockIdx.y * gridDim.x);
  const int nchunk = (int)(gridDim.x * gridDim.y) >> 3;
  const int swz = (lin & 7) * nchunk + (lin >> 3);
  const int bh = swz >> 5, b = bh >> 4, h = bh & 15;
  const int q0 = (31 - (swz & 31)) * 64;
  const int qw = q0 + w * 16;
  const u16* ql = qlat + (size_t)bh * Tn * 64;
  const u16* kl = klat + (size_t)bh * Tn * 64;
  const u16* vt = vlatT + (size_t)bh * 64 * Tn;
  const int l15 = lane & 15, lg = lane >> 4;

  half8 qf[2];
#pragma unroll
  for (int ks = 0; ks < 2; ++ks)
    qf[ks] = *(const half8*)(const void*)(ql + (size_t)(qw + l15) * 64 + (ks * 4 + lg) * 8);

  f32x4 accO[4];
#pragma unroll
  for (int mi = 0; mi < 4; ++mi) accO[mi] = (f32x4){0.f, 0.f, 0.f, 0.f};
  float mrow = -1e30f, lrow = 0.f;

  const int srow = tid >> 2, spair = tid & 3;
  u16* ksw = &Ks[srow * 72 + spair * 16];
  u16* vsw = &Vs[srow * 72 + spair * 16];
  const u16* kgp = kl + (size_t)srow * 64 + spair * 16;
  const u16* vgp = vt + (size_t)srow * Tn + spair * 16;

  ushort8 kr0 = *(const ushort8*)(kgp);
  ushort8 kr1 = *(const ushort8*)(kgp + 8);
  ushort8 vr0 = *(const ushort8*)(vgp);
  ushort8 vr1 = *(const ushort8*)(vgp + 8);

  const int ntiles = q0 / 64 + 1;
  for (int kt = 0; kt < ntiles; ++kt) {
    const int k0 = kt * 64;
    __syncthreads();
    *(ushort8*)ksw       = kr0;
    *(ushort8*)(ksw + 8) = kr1;
    *(ushort8*)vsw       = vr0;
    *(ushort8*)(vsw + 8) = vr1;
    __syncthreads();
    {
      int kn = k0 + 64; kn = kn > (int)Tn - 64 ? (int)Tn - 64 : kn;
      kr0 = *(const ushort8*)(kgp + (size_t)kn * 64);
      kr1 = *(const ushort8*)(kgp + (size_t)kn * 64 + 8);
      vr0 = *(const ushort8*)(vgp + kn);
      vr1 = *(const ushort8*)(vgp + kn + 8);
    }
    f32x4 s4[4];
#pragma unroll
    for (int mi = 0; mi < 4; ++mi) s4[mi] = (f32x4){0.f, 0.f, 0.f, 0.f};
    __builtin_amdgcn_s_setprio(1);
#pragma unroll
    for (int ks = 0; ks < 2; ++ks) {
      half8 kf[4];
#pragma unroll
      for (int mi = 0; mi < 4; ++mi)
        kf[mi] = *(const half8*)(const void*)&Ks[(mi * 16 + l15) * 72 + (ks * 4 + lg) * 8];
#pragma unroll
      for (int mi = 0; mi < 4; ++mi)
        s4[mi] = __builtin_amdgcn_mfma_f32_16x16x32_f16(kf[mi], qf[ks], s4[mi], 0, 0, 0);
    }
    __builtin_amdgcn_s_setprio(0);
    const bool needmask = (kt == ntiles - 1);
    const int qidx = qw + l15;
    float p[4][4];
    float tmax = -1e30f;
#pragma unroll
    for (int mi = 0; mi < 4; ++mi)
#pragma unroll
      for (int rr = 0; rr < 4; ++rr) {
        float v = s4[mi][rr] * SL2E;
        if (needmask && (k0 + mi * 16 + lg * 4 + rr > qidx)) v = -1e30f;
        p[mi][rr] = v;
        tmax = fmaxf(tmax, v);
      }
    tmax = fmaxf(tmax, __shfl_xor(tmax, 16));
    tmax = fmaxf(tmax, __shfl_xor(tmax, 32));
    if (!__all(tmax - mrow <= 8.f)) {
      float mnew = fmaxf(mrow, tmax);
      float alpha = exp2f(mrow - mnew);
      lrow *= alpha;
#pragma unroll
      for (int mi = 0; mi < 4; ++mi)
#pragma unroll
        for (int rr = 0; rr < 4; ++rr) accO[mi][rr] *= alpha;
      mrow = mnew;
    }
    float psum = 0.f;
    u16 ph[4][4];
#pragma unroll
    for (int mi = 0; mi < 4; ++mi)
#pragma unroll
      for (int rr = 0; rr < 4; ++rr) {
        float e = exp2f(p[mi][rr] - mrow);
        u16 hb = f16_rne(e);
        psum += f16_to_f(hb);
        ph[mi][rr] = hb;
      }
    psum += __shfl_xor(psum, 16);
    psum += __shfl_xor(psum, 32);
    lrow += psum;
    ushort8 pf[2];
#pragma unroll
    for (int ks = 0; ks < 2; ++ks) {
      ushort8 f;
#pragma unroll
      for (int rr = 0; rr < 4; ++rr) {
        f[rr]     = ph[2 * ks][rr];
        f[4 + rr] = ph[2 * ks + 1][rr];
      }
      pf[ks] = f;
    }
    __builtin_amdgcn_s_setprio(1);
#pragma unroll
    for (int ks = 0; ks < 2; ++ks) {
      half8 vf[4];
#pragma unroll
      for (int mi = 0; mi < 4; ++mi)
        vf[mi] = *(const half8*)(const void*)&Vs[(mi * 16 + l15) * 72 + (ks * 4 + lg) * 8];
#pragma unroll
      for (int mi = 0; mi < 4; ++mi)
        accO[mi] = __builtin_amdgcn_mfma_f32_16x16x32_f16(vf[mi], *(const half8*)&pf[ks], accO[mi], 0, 0, 0);
    }
    __builtin_amdgcn_s_setprio(0);
  }
  __syncthreads();  // all Ks/Vs reads done -> safe to reuse Ks as Os
  {
    float inv = 1.f / lrow;
    int qloc = w * 16 + l15;
#pragma unroll
    for (int mi = 0; mi < 4; ++mi) {
      int pbase = (mi >> 1) * 32 + lg * 8 + (mi & 1) * 4;
      ushort4v u;
#pragma unroll
      for (int rr = 0; rr < 4; ++rr) u[rr] = f16_rne(accO[mi][rr] * inv);
      *(ushort4v*)&Os[qloc][pbase] = u;
    }
  }
  __syncthreads();
  {
    int rid = tid >> 2, seg = tid & 3;
    u16* dstp = oh + ((size_t)(b * Tn + q0 + rid)) * 1024 + h * 64 + seg * 16;
#pragma unroll
    for (int g = 0; g < 2; ++g)
      *(ushort8*)(dstp + g * 8) = *(const ushort8*)&Os[rid][seg * 16 + g * 8];
  }
}

// ---------------------------------------------------------------------------
extern "C" void kernel_launch(void* const* d_in, const int* in_sizes, int n_in,
                              void* d_out, int out_size, void* d_ws, size_t ws_size,
                              hipStream_t stream) {
  const float* x     = (const float*)d_in[0];
  const float* freqs = (const float*)d_in[1];
  const float* Wq  = (const float*)d_in[3];  const float* bq  = (const float*)d_in[4];
  const float* Wk  = (const float*)d_in[5];  const float* bk  = (const float*)d_in[6];
  const float* Wv  = (const float*)d_in[7];  const float* bv  = (const float*)d_in[8];
  const float* Wo  = (const float*)d_in[9];  const float* bo  = (const float*)d_in[10];
  const float* Wcq = (const float*)d_in[11]; const float* bcq = (const float*)d_in[12];
  const float* Wck = (const float*)d_in[13]; const float* bck = (const float*)d_in[14];
  const float* Wcv = (const float*)d_in[15]; const float* bcv = (const float*)d_in[16];
  const float* Wd  = (const float*)d_in[17]; const float* bd  = (const float*)d_in[18];
  float* out = (float*)d_out;

  const size_t BT = (size_t)Bsz * Tn;          // 4096
  const size_t nQ = BT * Dn;                   // 8.39M
  const size_t nL = BT * Hn * Ln;              // 4.19M
  const size_t nWT = (size_t)5120 * 2048;      // 10.49M

  char* ws = (char*)d_ws;
  u16* xf   = (u16*)ws;
  u16* WTf  = xf + nQ;
  float* Wvf = (float*)(WTf + nWT);
  u16* Qh   = (u16*)(Wvf + (size_t)2048 * 1024);
  u16* Kh   = Qh + nQ;
  u16* vlat = Kh + nQ;
  float* bias_vf  = (float*)(vlat + (size_t)4096 * 1024);
  float* bias_out = bias_vf + 1024;
  u16* qlat  = (u16*)(bias_out + 2048);
  u16* klat  = qlat + nL;
  u16* vlatT = klat + nL;
  u16* oh = (u16*)(vlatT + nL);                        // [4096][1024] f16
  float* Wdo = (float*)(oh + (size_t)4096 * 1024);
  u16* WdoT = (u16*)(Wdo + (size_t)1024 * 2048);
  u16* WcqT = WdoT + (size_t)2048 * 1024;
  u16* WckT = WcqT + (size_t)64 * 128;

  dim3 blk(256);
  int nblkA = (int)(nQ / 8);

  // stage 1: operand prep
  split_h<<<(nblkA + 255) / 256, blk, 0, stream>>>(x, xf, nblkA, Dn);
  fold64<<<dim3(32, 16), blk, 0, stream>>>(Wv, 2048, 64 * 2048, 128,
                                           Wcv, 64, 0, 0,
                                           Wvf, 1024, 64 * 1024, 64);
  transpose_h2<<<dim3(64, 64, 2), blk, 0, stream>>>(Wq, Wk, WTf,
                                                    WTf + (size_t)2048 * 2048, 2048, 2048);
  transpose_h2<<<dim3(64, 32, 1), blk, 0, stream>>>(Wvf, Wvf, WTf + (size_t)4096 * 2048,
                                                    WTf + (size_t)4096 * 2048, 2048, 1024);
  transpose_h2<<<dim3(4, 2, 2), blk, 0, stream>>>(Wcq, Wck, WcqT, WckT, 128, 64);
  bias_prep<<<33, blk, 0, stream>>>(bv, Wcv, bcv, bd, Wo, bo, bias_vf, bias_out);

  // stage 2: fused Q/K/V-latent GEMM (N=5120, fp16, BK=64, 8 waves)
  gemm_qkv<<<dim3(40, 32), dim3(512), 0, stream>>>(xf, WTf, Qh, Kh, vlat,
                                                   bq, bk, bias_vf, 2048);

  // stage 3: latent Q/K (RoPE fused, MFMA, paired) + V transpose
  compress_qk_mfma<<<dim3(Tn / 64, Bsz * Hn, 2), blk, 0, stream>>>(
      Qh, Kh, WcqT, WckT, bcq, bck, freqs, qlat, klat);
  transpose_v<<<dim3(Tn / 64, Bsz * Hn), blk, 0, stream>>>(vlat, vlatT);

  // stage 4: attention (QBLK=64, fp16 MFMA, defer-max, XCD-chunked, fused oh)
  attn_mfma<<<dim3(Tn / 64, Bsz * Hn), blk, 0, stream>>>(qlat, klat, vlatT, oh);

  // stage 5: folded decompress+output projection (BK=64, 8 waves)
  fold64<<<dim3(32, 16), blk, 0, stream>>>(Wd, 128, 0, 0,
                                           Wo, 2048, 64, 128 * 2048,
                                           Wdo, 2048, 64, 64 * 2048);
  transpose_h2<<<dim3(32, 64, 1), blk, 0, stream>>>(Wdo, Wdo, WdoT, WdoT, 1024, 2048);
  gemm_f16<<<dim3(16, 32), dim3(512), 0, stream>>>(oh, WdoT, bias_out, out, (int)BT, 2048, 1024);
}